// Round 1
// baseline (232.257 us; speedup 1.0000x reference)
//
#include <hip/hip_runtime.h>

#define ROWS 4096
#define NCOL 8192
#define THREADS 512
#define WAVES (THREADS / 64)            // 8
#define F4PT (NCOL / (THREADS * 4))     // 4 float4 per thread
#define CAP 512                         // candidate list capacity (== THREADS)

__global__ __launch_bounds__(THREADS, 8)
void sparsemax_kernel(const float* __restrict__ x, float* __restrict__ out) {
    const int row = blockIdx.x;
    const size_t base = (size_t)row * NCOL;
    const float4* __restrict__ xr = (const float4*)(x + base);
    float4* __restrict__ outr = (float4*)(out + base);
    const int tid = threadIdx.x;
    const int wave = tid >> 6;
    const int lane = tid & 63;

    __shared__ float swv[WAVES];
    __shared__ int   swk[WAVES];
    __shared__ float cand[CAP];
    __shared__ int   scount;

    // init (covered by barrier (1))
    cand[tid] = -INFINITY;              // THREADS == CAP: one entry each
    if (tid == 0) scount = 0;

    // ---- Load entire row into registers (coalesced float4) ----
    float4 v[F4PT];
#pragma unroll
    for (int j = 0; j < F4PT; ++j) v[j] = xr[tid + THREADS * j];

    // ---- Block max ----
    float m = -INFINITY;
#pragma unroll
    for (int j = 0; j < F4PT; ++j)
        m = fmaxf(m, fmaxf(fmaxf(v[j].x, v[j].y), fmaxf(v[j].z, v[j].w)));
#pragma unroll
    for (int off = 32; off > 0; off >>= 1)
        m = fmaxf(m, __shfl_xor(m, off, 64));
    if (lane == 0) swv[wave] = m;
    __syncthreads();                                   // (1)

    float mm = swv[0];
#pragma unroll
    for (int w = 1; w < WAVES; ++w) mm = fmaxf(mm, swv[w]);
    const float t0 = mm - 1.0f;        // tau >= max-1, so {x > t0} contains support

    // ---- Single gather pass: candidates into LDS (typically ~5 of 8192) ----
#pragma unroll
    for (int j = 0; j < F4PT; ++j) {
        float4 q = v[j];
        if (q.x > t0) { int p = atomicAdd(&scount, 1); if (p < CAP) cand[p] = q.x; }
        if (q.y > t0) { int p = atomicAdd(&scount, 1); if (p < CAP) cand[p] = q.y; }
        if (q.z > t0) { int p = atomicAdd(&scount, 1); if (p < CAP) cand[p] = q.z; }
        if (q.w > t0) { int p = atomicAdd(&scount, 1); if (p < CAP) cand[p] = q.w; }
    }
    __syncthreads();                                   // (2)

    const int k0 = scount;
    float t = t0;

    if (k0 <= CAP) {
        // Every wave redundantly runs Michelot on the tiny list — shuffle-only,
        // zero barriers, identical result in all waves.
        float c[CAP / 64];                             // static-indexed (no scratch)
#pragma unroll
        for (int i = 0; i < CAP / 64; ++i) c[i] = cand[lane + 64 * i];
        int prev_k = -1;
        for (int it = 0; it < 48; ++it) {
            float s = 0.0f; int k = 0;
#pragma unroll
            for (int i = 0; i < CAP / 64; ++i) {
                float q = c[i];
                if (q > t) { s += q; ++k; }            // -inf pads never pass
            }
#pragma unroll
            for (int off = 32; off > 0; off >>= 1) {   // butterfly: total in all lanes
                s += __shfl_xor(s, off, 64);
                k += __shfl_xor(k, off, 64);
            }
            float tn = (s - 1.0f) / (float)k;
            if (k == prev_k) break;                    // support stable => tau exact
            prev_k = k; t = tn;
        }
    } else {
        // Exact fallback (candidate overflow — astronomically rare for this data):
        // block-wide Michelot over the register-resident row.
        int prev_k = -1;
        for (int it = 0; it < 64; ++it) {
            float s = 0.0f; int k = 0;
#pragma unroll
            for (int j = 0; j < F4PT; ++j) {
                float4 q = v[j];
                if (q.x > t) { s += q.x; ++k; }
                if (q.y > t) { s += q.y; ++k; }
                if (q.z > t) { s += q.z; ++k; }
                if (q.w > t) { s += q.w; ++k; }
            }
#pragma unroll
            for (int off = 32; off > 0; off >>= 1) {
                s += __shfl_xor(s, off, 64);
                k += __shfl_xor(k, off, 64);
            }
            if (lane == 0) { swv[wave] = s; swk[wave] = k; }
            __syncthreads();
            float st = 0.0f; int kt = 0;
#pragma unroll
            for (int w = 0; w < WAVES; ++w) { st += swv[w]; kt += swk[w]; }
            __syncthreads();
            float tn = (st - 1.0f) / (float)kt;
            if (kt == prev_k) break;
            prev_k = kt; t = tn;
        }
    }

    // ---- Epilogue: out = max(x - tau, 0) ----
#pragma unroll
    for (int j = 0; j < F4PT; ++j) {
        float4 q = v[j];
        float4 r;
        r.x = fmaxf(q.x - t, 0.0f);
        r.y = fmaxf(q.y - t, 0.0f);
        r.z = fmaxf(q.z - t, 0.0f);
        r.w = fmaxf(q.w - t, 0.0f);
        outr[tid + THREADS * j] = r;
    }
}

extern "C" void kernel_launch(void* const* d_in, const int* in_sizes, int n_in,
                              void* d_out, int out_size, void* d_ws, size_t ws_size,
                              hipStream_t stream) {
    const float* x = (const float*)d_in[0];
    float* out = (float*)d_out;
    sparsemax_kernel<<<ROWS, THREADS, 0, stream>>>(x, out);
}